// Round 1
// baseline (63.718 us; speedup 1.0000x reference)
//
#include <hip/hip_runtime.h>

// Problem constants (fixed in reference source)
#define NGRAPH 2048
#define TURNS  6
#define NPT    48
#define NHID   128
#define NC4    (NHID / 4)     // 32 float4 columns per node row
#define BN_EPS 1e-5f

__device__ __forceinline__ float4 f4max(float4 a, float4 b) {
    return make_float4(fmaxf(a.x, b.x), fmaxf(a.y, b.y), fmaxf(a.z, b.z), fmaxf(a.w, b.w));
}
__device__ __forceinline__ float4 f4min(float4 a, float4 b) {
    return make_float4(fminf(a.x, b.x), fminf(a.y, b.y), fminf(a.z, b.z), fminf(a.w, b.w));
}
__device__ __forceinline__ float4 f4add(float4 a, float4 b) {
    return make_float4(a.x + b.x, a.y + b.y, a.z + b.z, a.w + b.w);
}

// One block per graph. 192 threads = 6 turns x 32 float4-columns.
// Phase 1: per-(turn, col) segment max/min over 48 contiguous rows (coalesced float4).
// Phase 2: combine even-turn maxes (x1) and odd-turn mins (x2) -> 256-vec, BN1.
// Phase 3: fused MLP head: 64 threads x one W1-row dot each, ReLU, BN2,
//          64-lane shuffle-reduce dot with W4, + b4 -> out[g].
__global__ __launch_bounds__(192) void ggru_readout_mlp(
    const float* __restrict__ hp,
    const float* __restrict__ W1, const float* __restrict__ b1,
    const float* __restrict__ W4, const float* __restrict__ b4,
    const float* __restrict__ bn1_g, const float* __restrict__ bn1_b,
    const float* __restrict__ bn2_g, const float* __restrict__ bn2_b,
    float* __restrict__ out)
{
    __shared__ float4 segres[TURNS][NC4];
    __shared__ float  xbn[2 * NHID];   // BN1-applied concat [x1 | x2]

    const int g    = blockIdx.x;
    const int tid  = threadIdx.x;
    const int col  = tid & 31;         // float4 column 0..31
    const int turn = tid >> 5;         // 0..5

    // Rows for (g, turn): [g*TURNS*NPT + turn*NPT, +NPT)
    const float4* rowbase = reinterpret_cast<const float4*>(hp)
                          + (size_t)(g * TURNS + turn) * NPT * NC4 + col;

    float4 acc = rowbase[0];
    if ((turn & 1) == 0) {
        #pragma unroll 4
        for (int r = 1; r < NPT; ++r)
            acc = f4max(acc, rowbase[r * NC4]);
    } else {
        #pragma unroll 4
        for (int r = 1; r < NPT; ++r)
            acc = f4min(acc, rowbase[r * NC4]);
    }
    segres[turn][col] = acc;
    __syncthreads();

    if (tid < 64) {
        float4 s;
        if (tid < 32) {
            // x1: sum of maxes over even turns 0,2,4  -> features [0,128)
            s = f4add(f4add(segres[0][tid], segres[2][tid]), segres[4][tid]);
        } else {
            // x2: sum of mins over odd turns 1,3,5    -> features [128,256)
            int c = tid - 32;
            s = f4add(f4add(segres[1][c], segres[3][c]), segres[5][c]);
        }
        // BN1 (eval, single channel): x * (gamma/sqrt(1+eps)) + beta
        const float s1 = bn1_g[0] / sqrtf(1.0f + BN_EPS);
        const float t1 = bn1_b[0];
        s.x = s.x * s1 + t1;
        s.y = s.y * s1 + t1;
        s.z = s.z * s1 + t1;
        s.w = s.w * s1 + t1;
        reinterpret_cast<float4*>(xbn)[tid] = s;
    }
    __syncthreads();

    if (tid < 64) {
        // y[h] = relu(dot(W1[h,:], xbn) + b1[h])
        float acc2 = b1[tid];
        const float4* w  = reinterpret_cast<const float4*>(W1 + tid * (2 * NHID));
        const float4* xv = reinterpret_cast<const float4*>(xbn);
        #pragma unroll 8
        for (int k = 0; k < (2 * NHID) / 4; ++k) {
            const float4 wv = w[k];
            const float4 x  = xv[k];   // LDS broadcast (all lanes same addr)
            acc2 += wv.x * x.x + wv.y * x.y + wv.z * x.z + wv.w * x.w;
        }
        float y = fmaxf(acc2, 0.0f);
        const float s2 = bn2_g[0] / sqrtf(1.0f + BN_EPS);
        y = y * s2 + bn2_b[0];

        float p = y * W4[tid];
        #pragma unroll
        for (int off = 32; off > 0; off >>= 1)
            p += __shfl_down(p, off, 64);
        if (tid == 0)
            out[g] = p + b4[0];
    }
}

extern "C" void kernel_launch(void* const* d_in, const int* in_sizes, int n_in,
                              void* d_out, int out_size, void* d_ws, size_t ws_size,
                              hipStream_t stream) {
    (void)in_sizes; (void)n_in; (void)d_ws; (void)ws_size; (void)out_size;
    const float* hp    = (const float*)d_in[0];
    // d_in[1] = graph_ids, d_in[2] = turn_ids: layout is deterministic
    // (seg = idx/48, contiguous), so the index arrays are not needed.
    const float* W1    = (const float*)d_in[3];
    const float* b1    = (const float*)d_in[4];
    const float* W4    = (const float*)d_in[5];
    const float* b4    = (const float*)d_in[6];
    const float* bn1_g = (const float*)d_in[7];
    const float* bn1_b = (const float*)d_in[8];
    const float* bn2_g = (const float*)d_in[9];
    const float* bn2_b = (const float*)d_in[10];
    float* out = (float*)d_out;

    hipLaunchKernelGGL(ggru_readout_mlp, dim3(NGRAPH), dim3(192), 0, stream,
                       hp, W1, b1, W4, b4, bn1_g, bn1_b, bn2_g, bn2_b, out);
}

// Round 2
// 58.953 us; speedup vs baseline: 1.0808x; 1.0808x over previous
//
#include <hip/hip_runtime.h>

// Problem constants (fixed in reference source)
#define NGRAPH 2048
#define TURNS  6
#define NPT    48
#define NHID   128
#define NC4    (NHID / 4)     // 32 float4 columns per node row
#define BN_EPS 1e-5f

typedef float f32x4 __attribute__((ext_vector_type(4)));

__device__ __forceinline__ f32x4 f4max(f32x4 a, f32x4 b) {
    f32x4 r;
    r.x = fmaxf(a.x, b.x); r.y = fmaxf(a.y, b.y);
    r.z = fmaxf(a.z, b.z); r.w = fmaxf(a.w, b.w);
    return r;
}
__device__ __forceinline__ f32x4 f4min(f32x4 a, f32x4 b) {
    f32x4 r;
    r.x = fminf(a.x, b.x); r.y = fminf(a.y, b.y);
    r.z = fminf(a.z, b.z); r.w = fminf(a.w, b.w);
    return r;
}

// One block per graph. 384 threads = 2 row-halves x 6 turns x 32 float4-cols.
// Phase 1: each thread reduces 24 contiguous-stride rows of its (turn,col)
//          column (max for even turns, min for odd), non-temporal float4 loads.
// Phase 2: merge halves, combine even-turn maxes (x1) / odd-turn mins (x2),
//          BN1 -> 256-wide xbn in LDS.
// Phase 3: 64 threads x one W1-row dot, ReLU, BN2, 64-lane shuffle dot with
//          W4, +b4 -> out[g].
__global__ __launch_bounds__(384) void ggru_readout_mlp(
    const float* __restrict__ hp,
    const float* __restrict__ W1, const float* __restrict__ b1,
    const float* __restrict__ W4, const float* __restrict__ b4,
    const float* __restrict__ bn1_g, const float* __restrict__ bn1_b,
    const float* __restrict__ bn2_g, const float* __restrict__ bn2_b,
    float* __restrict__ out)
{
    __shared__ f32x4 segres[2][TURNS][NC4];
    __shared__ float xbn[2 * NHID];   // BN1-applied concat [x1 | x2]

    const int g    = blockIdx.x;
    const int tid  = threadIdx.x;
    const int col  = tid & 31;          // float4 column 0..31
    const int tt   = tid >> 5;          // 0..11
    const int half = (tt >= TURNS) ? 1 : 0;
    const int turn = tt - TURNS * half; // 0..5

    // Rows for (g, turn): [g*TURNS*NPT + turn*NPT, +NPT); this thread takes
    // rows [half*24, half*24+24).
    const f32x4* rowbase = reinterpret_cast<const f32x4*>(hp)
                         + ((size_t)(g * TURNS + turn) * NPT + half * (NPT / 2)) * NC4
                         + col;

    f32x4 acc = __builtin_nontemporal_load(&rowbase[0]);
    if ((turn & 1) == 0) {
        #pragma unroll 8
        for (int r = 1; r < NPT / 2; ++r)
            acc = f4max(acc, __builtin_nontemporal_load(&rowbase[r * NC4]));
    } else {
        #pragma unroll 8
        for (int r = 1; r < NPT / 2; ++r)
            acc = f4min(acc, __builtin_nontemporal_load(&rowbase[r * NC4]));
    }
    segres[half][turn][col] = acc;
    __syncthreads();

    if (tid < 64) {
        const int c = tid & 31;
        f32x4 s;
        if (tid < 32) {
            // x1: sum over even turns of max(half0, half1)  -> features [0,128)
            f32x4 t0 = f4max(segres[0][0][c], segres[1][0][c]);
            f32x4 t2 = f4max(segres[0][2][c], segres[1][2][c]);
            f32x4 t4 = f4max(segres[0][4][c], segres[1][4][c]);
            s = t0 + t2 + t4;
        } else {
            // x2: sum over odd turns of min(half0, half1)   -> features [128,256)
            f32x4 t1 = f4min(segres[0][1][c], segres[1][1][c]);
            f32x4 t3 = f4min(segres[0][3][c], segres[1][3][c]);
            f32x4 t5 = f4min(segres[0][5][c], segres[1][5][c]);
            s = t1 + t3 + t5;
        }
        // BN1 (eval, single channel): x * (gamma/sqrt(1+eps)) + beta
        const float s1 = bn1_g[0] / sqrtf(1.0f + BN_EPS);
        const float t1 = bn1_b[0];
        s = s * s1;
        s.x += t1; s.y += t1; s.z += t1; s.w += t1;
        reinterpret_cast<f32x4*>(xbn)[tid] = s;
    }
    __syncthreads();

    if (tid < 64) {
        // y[h] = relu(dot(W1[h,:], xbn) + b1[h])
        float acc2 = b1[tid];
        const f32x4* w  = reinterpret_cast<const f32x4*>(W1 + tid * (2 * NHID));
        const f32x4* xv = reinterpret_cast<const f32x4*>(xbn);
        #pragma unroll 8
        for (int k = 0; k < (2 * NHID) / 4; ++k) {
            const f32x4 wv = w[k];
            const f32x4 x  = xv[k];   // LDS broadcast (all lanes same addr)
            acc2 += wv.x * x.x + wv.y * x.y + wv.z * x.z + wv.w * x.w;
        }
        float y = fmaxf(acc2, 0.0f);
        const float s2 = bn2_g[0] / sqrtf(1.0f + BN_EPS);
        y = y * s2 + bn2_b[0];

        float p = y * W4[tid];
        #pragma unroll
        for (int off = 32; off > 0; off >>= 1)
            p += __shfl_down(p, off, 64);
        if (tid == 0)
            out[g] = p + b4[0];
    }
}

extern "C" void kernel_launch(void* const* d_in, const int* in_sizes, int n_in,
                              void* d_out, int out_size, void* d_ws, size_t ws_size,
                              hipStream_t stream) {
    (void)in_sizes; (void)n_in; (void)d_ws; (void)ws_size; (void)out_size;
    const float* hp    = (const float*)d_in[0];
    // d_in[1] = graph_ids, d_in[2] = turn_ids: layout is deterministic
    // (seg = idx/48, contiguous), so the index arrays are not needed.
    const float* W1    = (const float*)d_in[3];
    const float* b1    = (const float*)d_in[4];
    const float* W4    = (const float*)d_in[5];
    const float* b4    = (const float*)d_in[6];
    const float* bn1_g = (const float*)d_in[7];
    const float* bn1_b = (const float*)d_in[8];
    const float* bn2_g = (const float*)d_in[9];
    const float* bn2_b = (const float*)d_in[10];
    float* out = (float*)d_out;

    hipLaunchKernelGGL(ggru_readout_mlp, dim3(NGRAPH), dim3(384), 0, stream,
                       hp, W1, b1, W4, b4, bn1_g, bn1_b, bn2_g, bn2_b, out);
}

// Round 3
// 56.399 us; speedup vs baseline: 1.1298x; 1.0453x over previous
//
#include <hip/hip_runtime.h>

// Problem constants (fixed in reference source)
#define NGRAPH 2048
#define TURNS  6
#define NPT    48
#define NHID   128
#define NC4    (NHID / 4)     // 32 float4 columns per node row
#define BN_EPS 1e-5f

typedef float f32x4 __attribute__((ext_vector_type(4)));

__device__ __forceinline__ f32x4 f4max(f32x4 a, f32x4 b) {
    f32x4 r;
    r.x = fmaxf(a.x, b.x); r.y = fmaxf(a.y, b.y);
    r.z = fmaxf(a.z, b.z); r.w = fmaxf(a.w, b.w);
    return r;
}
__device__ __forceinline__ f32x4 f4min(f32x4 a, f32x4 b) {
    f32x4 r;
    r.x = fminf(a.x, b.x); r.y = fminf(a.y, b.y);
    r.z = fminf(a.z, b.z); r.w = fminf(a.w, b.w);
    return r;
}
__device__ __forceinline__ f32x4 f4shflxor32(f32x4 a) {
    f32x4 r;
    r.x = __shfl_xor(a.x, 32, 64);
    r.y = __shfl_xor(a.y, 32, 64);
    r.z = __shfl_xor(a.z, 32, 64);
    r.w = __shfl_xor(a.w, 32, 64);
    return r;
}

// One block per graph, 384 threads = 6 waves, one wave per turn.
// Phase 1: wave w streams turn w's 48x128 f32 block as 24 contiguous 1 KB
//          chunks (2 rows each; lanes 0-31 = even row cols, 32-63 = odd row
//          cols). 4 independent accumulator chains, then shfl_xor(32) merge.
// Phase 2: combine even-turn maxes (x1) / odd-turn mins (x2), BN1 -> xbn.
// Phase 3: 64 threads x one W1-row dot, ReLU, BN2, 64-lane shuffle dot with
//          W4, +b4 -> out[g].
__global__ __launch_bounds__(384) void ggru_readout_mlp(
    const float* __restrict__ hp,
    const float* __restrict__ W1, const float* __restrict__ b1,
    const float* __restrict__ W4, const float* __restrict__ b4,
    const float* __restrict__ bn1_g, const float* __restrict__ bn1_b,
    const float* __restrict__ bn2_g, const float* __restrict__ bn2_b,
    float* __restrict__ out)
{
    __shared__ f32x4 segres[TURNS][NC4];   // per-turn reduced row (cols 0..31)
    __shared__ float xbn[2 * NHID];        // BN1-applied concat [x1 | x2]

    const int g    = blockIdx.x;
    const int tid  = threadIdx.x;
    const int lane = tid & 63;
    const int turn = tid >> 6;             // wave id 0..5

    // (g, turn) block: 48 rows x 32 f4 = 1536 f4, contiguous. 24 chunks of
    // 64 f4 (1 KB); lane covers f4 #lane of each chunk.
    const f32x4* base = reinterpret_cast<const f32x4*>(hp)
                      + (size_t)(g * TURNS + turn) * (NPT * NC4) + lane;

    f32x4 a0 = base[0 * 64];
    f32x4 a1 = base[1 * 64];
    f32x4 a2 = base[2 * 64];
    f32x4 a3 = base[3 * 64];
    if ((turn & 1) == 0) {
        #pragma unroll
        for (int c = 4; c < 24; c += 4) {
            a0 = f4max(a0, base[(c + 0) * 64]);
            a1 = f4max(a1, base[(c + 1) * 64]);
            a2 = f4max(a2, base[(c + 2) * 64]);
            a3 = f4max(a3, base[(c + 3) * 64]);
        }
        a0 = f4max(f4max(a0, a1), f4max(a2, a3));
        a0 = f4max(a0, f4shflxor32(a0));   // merge even/odd row halves
    } else {
        #pragma unroll
        for (int c = 4; c < 24; c += 4) {
            a0 = f4min(a0, base[(c + 0) * 64]);
            a1 = f4min(a1, base[(c + 1) * 64]);
            a2 = f4min(a2, base[(c + 2) * 64]);
            a3 = f4min(a3, base[(c + 3) * 64]);
        }
        a0 = f4min(f4min(a0, a1), f4min(a2, a3));
        a0 = f4min(a0, f4shflxor32(a0));
    }
    if (lane < 32)
        segres[turn][lane] = a0;
    __syncthreads();

    if (tid < 64) {
        const int c = tid & 31;
        f32x4 s;
        if (tid < 32) {
            // x1: sum of maxes over even turns 0,2,4  -> features [0,128)
            s = segres[0][c] + segres[2][c] + segres[4][c];
        } else {
            // x2: sum of mins over odd turns 1,3,5    -> features [128,256)
            s = segres[1][c] + segres[3][c] + segres[5][c];
        }
        // BN1 (eval, single channel): x * (gamma/sqrt(1+eps)) + beta
        const float s1 = bn1_g[0] / sqrtf(1.0f + BN_EPS);
        const float t1 = bn1_b[0];
        s = s * s1;
        s.x += t1; s.y += t1; s.z += t1; s.w += t1;
        reinterpret_cast<f32x4*>(xbn)[tid] = s;
    }
    __syncthreads();

    if (tid < 64) {
        // y[h] = relu(dot(W1[h,:], xbn) + b1[h])
        float acc2 = b1[tid];
        const f32x4* w  = reinterpret_cast<const f32x4*>(W1 + tid * (2 * NHID));
        const f32x4* xv = reinterpret_cast<const f32x4*>(xbn);
        #pragma unroll 8
        for (int k = 0; k < (2 * NHID) / 4; ++k) {
            const f32x4 wv = w[k];
            const f32x4 x  = xv[k];   // LDS broadcast (all lanes same addr)
            acc2 += wv.x * x.x + wv.y * x.y + wv.z * x.z + wv.w * x.w;
        }
        float y = fmaxf(acc2, 0.0f);
        const float s2 = bn2_g[0] / sqrtf(1.0f + BN_EPS);
        y = y * s2 + bn2_b[0];

        float p = y * W4[tid];
        #pragma unroll
        for (int off = 32; off > 0; off >>= 1)
            p += __shfl_down(p, off, 64);
        if (tid == 0)
            out[g] = p + b4[0];
    }
}

extern "C" void kernel_launch(void* const* d_in, const int* in_sizes, int n_in,
                              void* d_out, int out_size, void* d_ws, size_t ws_size,
                              hipStream_t stream) {
    (void)in_sizes; (void)n_in; (void)d_ws; (void)ws_size; (void)out_size;
    const float* hp    = (const float*)d_in[0];
    // d_in[1] = graph_ids, d_in[2] = turn_ids: layout is deterministic
    // (seg = idx/48, contiguous), so the index arrays are not needed.
    const float* W1    = (const float*)d_in[3];
    const float* b1    = (const float*)d_in[4];
    const float* W4    = (const float*)d_in[5];
    const float* b4    = (const float*)d_in[6];
    const float* bn1_g = (const float*)d_in[7];
    const float* bn1_b = (const float*)d_in[8];
    const float* bn2_g = (const float*)d_in[9];
    const float* bn2_b = (const float*)d_in[10];
    float* out = (float*)d_out;

    hipLaunchKernelGGL(ggru_readout_mlp, dim3(NGRAPH), dim3(384), 0, stream,
                       hp, W1, b1, W4, b4, bn1_g, bn1_b, bn2_g, bn2_b, out);
}